// Round 1
// baseline (279.499 us; speedup 1.0000x reference)
//
#include <hip/hip_runtime.h>

// GaussianSplatting preprocess:
//   out = concat(positions [N,3], cov [N,3,3], alphas [N], sh [N,4]) flat f32
//   cov = R (S S^T) R^T = (R S)(R S)^T   (algebraic simplification, fewer FLOPs)
//   sh  = [SH_C0, c1*SH_C1, c0*SH_C1, c2*SH_C1]
// Memory-bound streaming kernel: 200 MB in, 136 MB out, ~53 us floor @ 6.3 TB/s.

#define SH_C0 0.282095f
#define SH_C1 0.488603f

__global__ __launch_bounds__(256) void gs_kernel(
    const float* __restrict__ pos,
    const float* __restrict__ col,
    const float* __restrict__ alp,
    const float* __restrict__ Rm,
    const float* __restrict__ Sm,
    float* __restrict__ out_pos,   // [n*3]
    float* __restrict__ out_cov,   // [n*9]
    float* __restrict__ out_alp,   // [n]
    float* __restrict__ out_sh,    // [n*4]
    int n)
{
    int i = blockIdx.x * blockDim.x + threadIdx.x;
    if (i >= n) return;

    // --- positions passthrough ---
    out_pos[3 * i + 0] = pos[3 * i + 0];
    out_pos[3 * i + 1] = pos[3 * i + 1];
    out_pos[3 * i + 2] = pos[3 * i + 2];

    // --- alphas passthrough ---
    out_alp[i] = alp[i];

    // --- sh coeffs ---
    float c0 = col[3 * i + 0];
    float c1 = col[3 * i + 1];
    float c2 = col[3 * i + 2];
    out_sh[4 * i + 0] = SH_C0;
    out_sh[4 * i + 1] = c1 * SH_C1;
    out_sh[4 * i + 2] = c0 * SH_C1;
    out_sh[4 * i + 3] = c2 * SH_C1;

    // --- cov = (R S)(R S)^T ---
    float r[9], s[9];
#pragma unroll
    for (int k = 0; k < 9; ++k) r[k] = Rm[9 * i + k];
#pragma unroll
    for (int k = 0; k < 9; ++k) s[k] = Sm[9 * i + k];

    float t[9];  // T = R @ S  (row-major 3x3)
#pragma unroll
    for (int a = 0; a < 3; ++a) {
#pragma unroll
        for (int b = 0; b < 3; ++b) {
            t[3 * a + b] = r[3 * a + 0] * s[0 + b]
                         + r[3 * a + 1] * s[3 + b]
                         + r[3 * a + 2] * s[6 + b];
        }
    }

#pragma unroll
    for (int a = 0; a < 3; ++a) {
#pragma unroll
        for (int b = 0; b < 3; ++b) {
            out_cov[9 * i + 3 * a + b] = t[3 * a + 0] * t[3 * b + 0]
                                       + t[3 * a + 1] * t[3 * b + 1]
                                       + t[3 * a + 2] * t[3 * b + 2];
        }
    }
}

extern "C" void kernel_launch(void* const* d_in, const int* in_sizes, int n_in,
                              void* d_out, int out_size, void* d_ws, size_t ws_size,
                              hipStream_t stream) {
    const float* pos = (const float*)d_in[0];  // [N,3]
    const float* col = (const float*)d_in[1];  // [N,3]
    const float* alp = (const float*)d_in[2];  // [N]
    const float* Rm  = (const float*)d_in[3];  // [N,3,3]
    const float* Sm  = (const float*)d_in[4];  // [N,3,3]

    int n = in_sizes[0] / 3;

    float* out = (float*)d_out;
    float* out_pos = out;             // n*3
    float* out_cov = out + 3 * n;     // n*9
    float* out_alp = out + 12 * n;    // n
    float* out_sh  = out + 13 * n;    // n*4

    int block = 256;
    int grid = (n + block - 1) / block;
    gs_kernel<<<grid, block, 0, stream>>>(pos, col, alp, Rm, Sm,
                                          out_pos, out_cov, out_alp, out_sh, n);
}